// Round 1
// baseline (34.336 us; speedup 1.0000x reference)
//
#include <hip/hip_runtime.h>
#include <math.h>

// Problem constants (from reference)
#define EMB  4096
#define HID  256
#define DOUT 4103
#define MEM  1024
#define BUF  2048
// NOUT = MEM*BUF + MEM*(MEM+1)/2 + 3*MEM = 2097152 + 524800 + 3072
#define NOUT 2625024

// Padded lp table layout: 6 heads, sizes {4,2,1,2048,1024,1024}, each +1 pad slot (=0.0)
// offsets into padded table: {0,5,8,10,2059,3084}, total 4109 floats
// act offsets: {0,4,6,7,2055,3079,4103}

// ---------------- layer 1: h = tanh(W1 @ ctx + b1), h[256] ----------------
__global__ void k_layer1(const float* __restrict__ ctx, const float* __restrict__ W1,
                         const float* __restrict__ b1, float* __restrict__ h) {
    int r = blockIdx.x;                      // 256 blocks, one row each
    const float* row = W1 + (size_t)r * EMB;
    float s = 0.f;
    // coalesced: thread t reads j = t, t+256, ... (16 iters)
    for (int j = threadIdx.x; j < EMB; j += 256)
        s += row[j] * ctx[j];
    // wave (64-lane) reduce then cross-wave via LDS
    for (int off = 32; off > 0; off >>= 1) s += __shfl_down(s, off);
    __shared__ float red[4];
    int lane = threadIdx.x & 63, w = threadIdx.x >> 6;
    if (lane == 0) red[w] = s;
    __syncthreads();
    if (threadIdx.x == 0) {
        float t = red[0] + red[1] + red[2] + red[3] + b1[r];
        h[r] = tanhf(t);
    }
}

// ---------------- layer 2: act = W2 @ h + b2, act[4103] ----------------
__global__ void k_layer2(const float* __restrict__ h, const float* __restrict__ W2,
                         const float* __restrict__ b2, float* __restrict__ act) {
    int r = blockIdx.x;                      // 4103 blocks, 64 threads (1 wave)
    const float* row = W2 + (size_t)r * HID;
    int t = threadIdx.x;
    float s = row[t]       * h[t]
            + row[t + 64]  * h[t + 64]
            + row[t + 128] * h[t + 128]
            + row[t + 192] * h[t + 192];
    for (int off = 32; off > 0; off >>= 1) s += __shfl_down(s, off);
    if (t == 0) act[r] = s + b2[r];
}

// ---------------- per-head log_softmax into padded lp table ----------------
__global__ void k_softmax(const float* __restrict__ act, float* __restrict__ lp) {
    const int offs[7] = {0, 4, 6, 7, 2055, 3079, 4103};
    const int poff[6] = {0, 5, 8, 10, 2059, 3084};
    int hd = blockIdx.x;                     // 6 blocks
    int o  = offs[hd];
    int n  = offs[hd + 1] - o;
    int po = poff[hd];

    __shared__ float sm[4], ss[4];
    int lane = threadIdx.x & 63, w = threadIdx.x >> 6;

    // max
    float m = -INFINITY;
    for (int j = threadIdx.x; j < n; j += 256) m = fmaxf(m, act[o + j]);
    for (int off = 32; off > 0; off >>= 1) m = fmaxf(m, __shfl_down(m, off));
    if (lane == 0) sm[w] = m;
    __syncthreads();
    m = fmaxf(fmaxf(sm[0], sm[1]), fmaxf(sm[2], sm[3]));

    // sum exp
    float s = 0.f;
    for (int j = threadIdx.x; j < n; j += 256) s += expf(act[o + j] - m);
    for (int off = 32; off > 0; off >>= 1) s += __shfl_down(s, off);
    if (lane == 0) ss[w] = s;
    __syncthreads();
    float lse = m + logf(ss[0] + ss[1] + ss[2] + ss[3]);

    // write lp + pad slot (0.0 at index n -> 'absent param')
    for (int j = threadIdx.x; j < n; j += 256) lp[po + j] = act[o + j] - lse;
    if (threadIdx.x == 0) lp[po + n] = 0.f;
}

// ---------------- fused gather-sum over all actions ----------------
__global__ void k_gather(const float* __restrict__ lp,
                         const int* __restrict__ ti,  const int* __restrict__ ui,
                         const int* __restrict__ bi,  const int* __restrict__ bfi,
                         const int* __restrict__ m1i, const int* __restrict__ m2i,
                         float* __restrict__ out) {
    int i = blockIdx.x * blockDim.x + threadIdx.x;
    if (i >= NOUT) return;
    out[i] = lp[0    + ti[i]]
           + lp[5    + ui[i]]
           + lp[8    + bi[i]]
           + lp[10   + bfi[i]]
           + lp[2059 + m1i[i]]
           + lp[3084 + m2i[i]];
}

extern "C" void kernel_launch(void* const* d_in, const int* in_sizes, int n_in,
                              void* d_out, int out_size, void* d_ws, size_t ws_size,
                              hipStream_t stream) {
    const float* ctx = (const float*)d_in[0];
    const float* W1  = (const float*)d_in[1];
    const float* b1  = (const float*)d_in[2];
    const float* W2  = (const float*)d_in[3];
    const float* b2  = (const float*)d_in[4];
    const int* ti  = (const int*)d_in[5];
    const int* ui  = (const int*)d_in[6];
    const int* bi  = (const int*)d_in[7];
    const int* bfi = (const int*)d_in[8];
    const int* m1i = (const int*)d_in[9];
    const int* m2i = (const int*)d_in[10];

    float* w   = (float*)d_ws;
    float* h   = w;            // [256]
    float* act = w + 256;      // [4103]
    float* lp  = w + 4359;     // [4109] padded lp tables

    k_layer1 <<<HID,  256, 0, stream>>>(ctx, W1, b1, h);
    k_layer2 <<<DOUT, 64,  0, stream>>>(h, W2, b2, act);
    k_softmax<<<6,    256, 0, stream>>>(act, lp);
    k_gather <<<(NOUT + 255) / 256, 256, 0, stream>>>(lp, ti, ui, bi, bfi, m1i, m2i,
                                                      (float*)d_out);
}

// Round 2
// 23.984 us; speedup vs baseline: 1.4316x; 1.4316x over previous
//
#include <hip/hip_runtime.h>
#include <math.h>

#define EMB  4096
#define HID  256
#define DOUT 4103
#define MEM  1024
#define BUF  2048
#define N_PUSH 2097152              // MEM*BUF
#define N_JOIN 524800               // MEM*(MEM+1)/2
#define JOIN_END 2621952            // N_PUSH + N_JOIN
#define NOUT 2625024                // + 3*MEM

// lp table (padded): a@0(5), u@5(3), bi@8(2), bf@10(2049), m1@2059(1025), m2@3084(1025) -> 4109

// ---------------- layer 1: h = tanh(W1 @ ctx + b1) ----------------
__global__ void k_layer1(const float* __restrict__ ctx, const float* __restrict__ W1,
                         const float* __restrict__ b1, float* __restrict__ h) {
    int r = blockIdx.x;                      // 256 blocks, one row each
    const float4* row4 = (const float4*)(W1 + (size_t)r * EMB);
    const float4* ctx4 = (const float4*)ctx;
    float s = 0.f;
    #pragma unroll
    for (int k = 0; k < 4; ++k) {            // 4096/4 = 1024 float4s, 256 threads
        float4 a = row4[threadIdx.x + k * 256];
        float4 c = ctx4[threadIdx.x + k * 256];
        s += a.x * c.x + a.y * c.y + a.z * c.z + a.w * c.w;
    }
    for (int off = 32; off > 0; off >>= 1) s += __shfl_down(s, off);
    __shared__ float red[4];
    int lane = threadIdx.x & 63, w = threadIdx.x >> 6;
    if (lane == 0) red[w] = s;
    __syncthreads();
    if (threadIdx.x == 0) {
        float t = red[0] + red[1] + red[2] + red[3] + b1[r];
        h[r] = tanhf(t);
    }
}

// ---------------- layer 2: act = W2 @ h + b2 ----------------
__global__ void k_layer2(const float* __restrict__ h, const float* __restrict__ W2,
                         const float* __restrict__ b2, float* __restrict__ act) {
    int r = blockIdx.x;                      // 4103 blocks, 1 wave each
    const float4* row4 = (const float4*)(W2 + (size_t)r * HID);
    const float4* h4   = (const float4*)h;
    int t = threadIdx.x;
    float4 a = row4[t], c = h4[t];
    float s = a.x * c.x + a.y * c.y + a.z * c.z + a.w * c.w;
    for (int off = 32; off > 0; off >>= 1) s += __shfl_down(s, off);
    if (t == 0) act[r] = s + b2[r];
}

// ---------------- per-head log_softmax into padded lp table ----------------
__global__ void k_softmax(const float* __restrict__ act, float* __restrict__ lp) {
    const int offs[7] = {0, 4, 6, 7, 2055, 3079, 4103};
    const int poff[6] = {0, 5, 8, 10, 2059, 3084};
    int hd = blockIdx.x;                     // 6 blocks
    int o  = offs[hd];
    int n  = offs[hd + 1] - o;
    int po = poff[hd];

    __shared__ float sm[4], ss[4];
    int lane = threadIdx.x & 63, w = threadIdx.x >> 6;

    float m = -INFINITY;
    for (int j = threadIdx.x; j < n; j += 256) m = fmaxf(m, act[o + j]);
    for (int off = 32; off > 0; off >>= 1) m = fmaxf(m, __shfl_down(m, off));
    if (lane == 0) sm[w] = m;
    __syncthreads();
    m = fmaxf(fmaxf(sm[0], sm[1]), fmaxf(sm[2], sm[3]));

    float s = 0.f;
    for (int j = threadIdx.x; j < n; j += 256) s += expf(act[o + j] - m);
    for (int off = 32; off > 0; off >>= 1) s += __shfl_down(s, off);
    if (lane == 0) ss[w] = s;
    __syncthreads();
    float lse = m + logf(ss[0] + ss[1] + ss[2] + ss[3]);

    for (int j = threadIdx.x; j < n; j += 256) lp[po + j] = act[o + j] - lse;
    if (threadIdx.x == 0) lp[po + n] = 0.f;
}

// ---------------- analytic output: no index reads, write-only ----------------
__device__ __forceinline__ int join_rowstart(int r) {
    // S(r) = r*MEM - r*(r-1)/2
    return r * MEM - (r * (r - 1)) / 2;
}

__device__ __forceinline__ float out_val(int i, const float* __restrict__ lp,
                                         float push_c, float join_c,
                                         float prod_c, float op0_c, float op1_c,
                                         int jr, int jstart) {
    if (i < N_PUSH) {
        int mem = 1023 - (i >> 11);
        int buf = 2047 - (i & 2047);
        return push_c + lp[10 + buf] + lp[2059 + mem];
    } else if (i < JOIN_END) {
        int k = i - N_PUSH;
        int j2 = jr + (k - jstart);
        return join_c + lp[2059 + jr] + lp[3084 + j2];
    } else {
        int k = i - JOIN_END;
        int mem1 = k / 3, r = k - mem1 * 3;
        float base = (r == 0) ? prod_c : (r == 1 ? op0_c : op1_c);
        return base + lp[2059 + mem1];
    }
}

__global__ void k_out(const float* __restrict__ lp, float* __restrict__ out) {
    int base = (blockIdx.x * 256 + threadIdx.x) * 4;
    if (base >= NOUT) return;

    // scalar constants (L1/L2-resident tiny table)
    float push_c = lp[0];                 // a_lp[0]  (+pads = 0)
    float join_c = lp[2] + lp[8];         // a_lp[2] + bi_lp[0]
    float prod_c = lp[3];                 // a_lp[3]
    float op0_c  = lp[1] + lp[5];         // a_lp[1] + u_lp[0]
    float op1_c  = lp[1] + lp[6];         // a_lp[1] + u_lp[1]

    // join-row decode once for the first element, then walk
    int jr = 0, jstart = 0;
    if (base + 3 >= N_PUSH && base < JOIN_END) {
        int k = max(base - N_PUSH, 0);
        double A = 2.0 * MEM + 1.0;
        int r = (int)((A - sqrt(A * A - 8.0 * (double)k)) * 0.5);
        if (r < 0) r = 0;
        if (r > MEM - 1) r = MEM - 1;
        while (r + 1 <= MEM - 1 && join_rowstart(r + 1) <= k) ++r;
        while (r > 0 && join_rowstart(r) > k) --r;
        jr = r; jstart = join_rowstart(r);
    }

    float4 v;
    float* vp = (float*)&v;
    #pragma unroll
    for (int e = 0; e < 4; ++e) {
        int i = base + e;
        // advance join row if we crossed a row boundary
        if (i >= N_PUSH && i < JOIN_END) {
            int k = i - N_PUSH;
            while (k - jstart >= MEM - jr) { jstart += MEM - jr; ++jr; }
        }
        vp[e] = out_val(i, lp, push_c, join_c, prod_c, op0_c, op1_c, jr, jstart);
    }
    *(float4*)(out + base) = v;
}

extern "C" void kernel_launch(void* const* d_in, const int* in_sizes, int n_in,
                              void* d_out, int out_size, void* d_ws, size_t ws_size,
                              hipStream_t stream) {
    const float* ctx = (const float*)d_in[0];
    const float* W1  = (const float*)d_in[1];
    const float* b1  = (const float*)d_in[2];
    const float* W2  = (const float*)d_in[3];
    const float* b2  = (const float*)d_in[4];

    float* w   = (float*)d_ws;
    float* h   = w;            // [256]
    float* act = w + 256;      // [4103]
    float* lp  = w + 4359;     // [4109] padded lp tables

    k_layer1 <<<HID,  256, 0, stream>>>(ctx, W1, b1, h);
    k_layer2 <<<DOUT, 64,  0, stream>>>(h, W2, b2, act);
    k_softmax<<<6,    256, 0, stream>>>(act, lp);
    k_out    <<<(NOUT / 4 + 255) / 256, 256, 0, stream>>>(lp, (float*)d_out);
}